// Round 14
// baseline (144.630 us; speedup 1.0000x reference)
//
#include <hip/hip_runtime.h>
#include <hip/hip_bf16.h>
#include <math.h>

namespace {

constexpr int kB = 32;
constexpr int kS = 2048;
constexpr int kI = 32;
constexpr int kW = 20;
constexpr int kH = 128;
constexpr int kNwin = kS - kW + 1;   // 2029
constexpr int kT = kS - 2 * kW;      // 2008
constexpr float kEps = 1e-5f;
constexpr int FCAP = 4096;
constexpr float kMargin = 1e-3f;

typedef __attribute__((ext_vector_type(8))) short short8;          // 8 bf16
typedef __attribute__((ext_vector_type(8))) unsigned short ush8;   // 16B unit
typedef __attribute__((ext_vector_type(4))) float f32x4;

__device__ __forceinline__ unsigned short f2bf(float f) {
    unsigned u = __builtin_bit_cast(unsigned, f);
    u += 0x7FFFu + ((u >> 16) & 1u);
    return (unsigned short)(u >> 16);
}
__device__ __forceinline__ float bf2f(unsigned short h) {
    unsigned u = ((unsigned)h) << 16;
    return __builtin_bit_cast(float, u);
}
__device__ __forceinline__ void split2(float v, unsigned short& hi, unsigned short& lo) {
    hi = f2bf(v);
    lo = f2bf(v - bf2f(hi));
}
__device__ __forceinline__ float gelu_exact(float v) {
    return 0.5f * v * (1.0f + erff(v * 0.70710678118654752440f));
}

// ---- workspace layout (bytes) ----
constexpr size_t ENCP_OFF = 0;                        // packed enc u32: 33.5 MB
constexpr size_t WETH_OFF = 33554432;                 // WencT hi [128][640]
constexpr size_t WETL_OFF = WETH_OFF + 163840;
constexpr size_t W1TH_OFF = WETL_OFF + 163840;        // W1T hi [128][256]
constexpr size_t W1TL_OFF = W1TH_OFF + 65536;
constexpr size_t W2TH_OFF = W1TL_OFF + 65536;         // W2T hi [64][128]
constexpr size_t W2TL_OFF = W2TH_OFF + 16384;
constexpr size_t FC_OFF   = W2TL_OFF + 16384;
constexpr size_t FL_OFF   = FC_OFF + 64;

// ================= prep: W transposes + hi/lo splits =================
__global__ void prep_kernel(const float* __restrict__ Wenc, const float* __restrict__ W1,
                            const float* __restrict__ W2,
                            unsigned short* __restrict__ WeTh, unsigned short* __restrict__ WeTl,
                            unsigned short* __restrict__ W1Th, unsigned short* __restrict__ W1Tl,
                            unsigned short* __restrict__ W2Th, unsigned short* __restrict__ W2Tl)
{
    const int tid = blockIdx.x * blockDim.x + threadIdx.x;
    const int nth = gridDim.x * blockDim.x;
    for (int i = tid; i < kH * 640; i += nth) {
        int n = i / 640, k = i - n * 640;
        split2(Wenc[(size_t)k * kH + n], WeTh[i], WeTl[i]);
    }
    for (int i = tid; i < kH * 256; i += nth) {
        int n = i >> 8, k = i & 255;
        split2(W1[(size_t)k * kH + n], W1Th[i], W1Tl[i]);
    }
    for (int i = tid; i < 64 * kH; i += nth) {
        int n = i >> 7, k = i & 127;
        split2(W2[(size_t)k * 64 + n], W2Th[i], W2Tl[i]);
    }
}

// ================= encoder: 256-row block, 8 waves x (32r x 128c) =================
constexpr int AP = 40;    // LDS pitch in ushorts (80B, 16B-aligned)
constexpr int EXR = 275;  // x rows staged (256 + 19)

__global__ __launch_bounds__(512, 2)
void enc_kernel(const float* __restrict__ x,
                const unsigned short* __restrict__ WeTh, const unsigned short* __restrict__ WeTl,
                const float* __restrict__ benc, const float* __restrict__ gma,
                const float* __restrict__ bta, unsigned* __restrict__ encp)
{
    __shared__ unsigned short xsh[EXR * AP];     // 11000 ush = 22000 B
    __shared__ unsigned short xsl[EXR * AP];
    __shared__ unsigned short wth[128 * AP];     // 5120 ush
    __shared__ unsigned short wtl[128 * AP];     // total 64480 B

    const int tid = threadIdx.x, b = blockIdx.y, t0 = blockIdx.x * 256;
    const int l = tid & 63, w = tid >> 6;        // wave w: rows w*32..+31, cols 0..127
    const int cb = l & 15, rg = l >> 4;

    // stage x rows t0..t0+274 (f32 -> hi/lo bf16)
    const float4* x4 = reinterpret_cast<const float4*>(x + (size_t)b * kS * kI);
    for (int i = tid; i < EXR * 8; i += 512) {
        int r = i >> 3, q = i & 7;
        int gr = t0 + r; if (gr > kS - 1) gr = kS - 1;
        float4 v = x4[gr * 8 + q];
        unsigned short h0, h1, h2, h3, l0, l1, l2, l3;
        split2(v.x, h0, l0); split2(v.y, h1, l1); split2(v.z, h2, l2); split2(v.w, h3, l3);
        *reinterpret_cast<uint2*>(&xsh[r * AP + q * 4]) =
            make_uint2((unsigned)h0 | ((unsigned)h1 << 16), (unsigned)h2 | ((unsigned)h3 << 16));
        *reinterpret_cast<uint2*>(&xsl[r * AP + q * 4]) =
            make_uint2((unsigned)l0 | ((unsigned)l1 << 16), (unsigned)l2 | ((unsigned)l3 << 16));
    }

    f32x4 acc[2][8];
    #pragma unroll
    for (int mi = 0; mi < 2; ++mi)
        #pragma unroll
        for (int nf = 0; nf < 8; ++nf) acc[mi][nf] = f32x4{0.f, 0.f, 0.f, 0.f};

    for (int kc = 0; kc < 20; ++kc) {            // K = 640 in chunks of 32
        __syncthreads();
        {   // stage W chunk (128 n x 32 k) hi/lo: exactly 512 units
            const int n = tid >> 2, q = tid & 3;
            const size_t so = (size_t)n * 640 + kc * 32 + q * 8;
            *reinterpret_cast<ush8*>(&wth[n * AP + q * 8]) =
                *reinterpret_cast<const ush8*>(WeTh + so);
            *reinterpret_cast<ush8*>(&wtl[n * AP + q * 8]) =
                *reinterpret_cast<const ush8*>(WeTl + so);
        }
        __syncthreads();
        const int a0o = (w * 32 + cb + kc) * AP + rg * 8;
        short8 a0h = *reinterpret_cast<const short8*>(&xsh[a0o]);
        short8 a0l = *reinterpret_cast<const short8*>(&xsl[a0o]);
        short8 a1h = *reinterpret_cast<const short8*>(&xsh[a0o + 16 * AP]);
        short8 a1l = *reinterpret_cast<const short8*>(&xsl[a0o + 16 * AP]);
        #pragma unroll
        for (int nf = 0; nf < 8; ++nf) {
            const int bo = (nf * 16 + cb) * AP + rg * 8;
            short8 bh = *reinterpret_cast<const short8*>(&wth[bo]);
            short8 bl = *reinterpret_cast<const short8*>(&wtl[bo]);
            acc[0][nf] = __builtin_amdgcn_mfma_f32_16x16x32_bf16(a0h, bh, acc[0][nf], 0, 0, 0);
            acc[0][nf] = __builtin_amdgcn_mfma_f32_16x16x32_bf16(a0l, bh, acc[0][nf], 0, 0, 0);
            acc[0][nf] = __builtin_amdgcn_mfma_f32_16x16x32_bf16(a0h, bl, acc[0][nf], 0, 0, 0);
            acc[1][nf] = __builtin_amdgcn_mfma_f32_16x16x32_bf16(a1h, bh, acc[1][nf], 0, 0, 0);
            acc[1][nf] = __builtin_amdgcn_mfma_f32_16x16x32_bf16(a1l, bh, acc[1][nf], 0, 0, 0);
            acc[1][nf] = __builtin_amdgcn_mfma_f32_16x16x32_bf16(a1h, bl, acc[1][nf], 0, 0, 0);
        }
    }

    // epilogue: C/D col = lane&15, row = (lane>>4)*4 + reg ; LN over cb-lanes ; GELU ; pack
    float bv[8], gv[8], btv[8];
    #pragma unroll
    for (int nf = 0; nf < 8; ++nf) {
        bv[nf]  = benc[nf * 16 + cb];
        gv[nf]  = gma[nf * 16 + cb];
        btv[nf] = bta[nf * 16 + cb];
    }
    #pragma unroll
    for (int mi = 0; mi < 2; ++mi) {
        #pragma unroll
        for (int r = 0; r < 4; ++r) {
            const int rl = w * 32 + mi * 16 + rg * 4 + r;
            const int t = t0 + rl;
            float h[8];
            float s = 0.f;
            #pragma unroll
            for (int nf = 0; nf < 8; ++nf) { h[nf] = acc[mi][nf][r] + bv[nf]; s += h[nf]; }
            s += __shfl_xor(s, 1); s += __shfl_xor(s, 2); s += __shfl_xor(s, 4); s += __shfl_xor(s, 8);
            const float mu = s * (1.f / 128.f);
            float s2 = 0.f;
            #pragma unroll
            for (int nf = 0; nf < 8; ++nf) { h[nf] -= mu; s2 += h[nf] * h[nf]; }
            s2 += __shfl_xor(s2, 1); s2 += __shfl_xor(s2, 2); s2 += __shfl_xor(s2, 4); s2 += __shfl_xor(s2, 8);
            const float rstd = 1.f / sqrtf(s2 * (1.f / 128.f) + kEps);
            if (t < kNwin) {
                unsigned* dst = encp + ((size_t)(b * kS + t)) * kH;
                #pragma unroll
                for (int nf = 0; nf < 8; ++nf) {
                    float v = gelu_exact(h[nf] * rstd * gv[nf] + btv[nf]);
                    unsigned short hi, lo;
                    split2(v, hi, lo);
                    dst[nf * 16 + cb] = (unsigned)hi | ((unsigned)lo << 16);
                }
            }
        }
    }
}

// ================= comparator: es staged ONCE packed; 64-row block, 4 waves =================
// pool bytes: phase1: es u32 [84][132] @0 (44352) | wt1h @44352 (10240) | wt1l @54592 (10240) -> 64832
//             phase2: z1h ush [64][136] @0 (17408) | z1l @17408 | w2h @34816 (5120) | w2l @39936
//             phase3: z2f f32 [64][68] @0 (17408)
constexpr int ESP = 132;   // es pitch in u32 (528 B, 16B-aligned; 2-way banks on frag reads)

__global__ __launch_bounds__(256, 2)
void cmp_kernel(const unsigned* __restrict__ encp,
                const unsigned short* __restrict__ W1Th, const unsigned short* __restrict__ W1Tl,
                const float* __restrict__ b1,
                const unsigned short* __restrict__ W2Th, const unsigned short* __restrict__ W2Tl,
                const float* __restrict__ b2, const float* __restrict__ W3,
                const float* __restrict__ b3, float* __restrict__ out,
                int* __restrict__ fcnt, unsigned* __restrict__ flist)
{
    __shared__ __align__(16) unsigned char poolb[64832];

    unsigned* es         = reinterpret_cast<unsigned*>(poolb);
    unsigned short* wt1h = reinterpret_cast<unsigned short*>(poolb + 44352);
    unsigned short* wt1l = reinterpret_cast<unsigned short*>(poolb + 54592);

    const int tid = threadIdx.x, b = blockIdx.y, t0 = blockIdx.x * 64;
    const int l = tid & 63, w = tid >> 6;        // wave w: rows w*16..+15
    const int cb = l & 15, rg = l >> 4;

    // stage enc rows [t0, t0+84) PACKED (raw copy, no unpack)
    for (int i = tid; i < 84 * 32; i += 256) {
        int r = i >> 5, u = i & 31;
        int gr = t0 + r; if (gr > kNwin - 1) gr = kNwin - 1;
        const uint4 v = *reinterpret_cast<const uint4*>(
            encp + ((size_t)(b * kS + gr)) * kH + u * 4);
        *reinterpret_cast<uint4*>(&es[r * ESP + u * 4]) = v;
    }

    // ---- layer 1: A[t][k] = enc[t + (k<128?0:20)][k&127], K=256 in 8 chunks of 32
    f32x4 acc1[8];
    #pragma unroll
    for (int nf = 0; nf < 8; ++nf) acc1[nf] = f32x4{0.f, 0.f, 0.f, 0.f};

    for (int kc = 0; kc < 8; ++kc) {
        __syncthreads();
        #pragma unroll
        for (int u = 0; u < 2; ++u) {            // stage W1 chunk (128 n x 32 k) hi/lo
            int i = tid + 256 * u;
            int n = i >> 2, q = i & 3;
            const size_t so = (size_t)n * 256 + kc * 32 + q * 8;
            *reinterpret_cast<ush8*>(&wt1h[n * AP + q * 8]) =
                *reinterpret_cast<const ush8*>(W1Th + so);
            *reinterpret_cast<ush8*>(&wt1l[n * AP + q * 8]) =
                *reinterpret_cast<const ush8*>(W1Tl + so);
        }
        __syncthreads();
        const int ro = (kc < 4) ? 0 : kW, co = (kc & 3) * 32;
        // A-fragment: packed u32 read + in-register unpack
        const unsigned* ep = es + (w * 16 + cb + ro) * ESP + co + rg * 8;
        const uint4 v0 = *reinterpret_cast<const uint4*>(ep);
        const uint4 v1 = *reinterpret_cast<const uint4*>(ep + 4);
        const uint4 ahw = make_uint4(
            (v0.x & 0xFFFFu) | ((v0.y & 0xFFFFu) << 16), (v0.z & 0xFFFFu) | ((v0.w & 0xFFFFu) << 16),
            (v1.x & 0xFFFFu) | ((v1.y & 0xFFFFu) << 16), (v1.z & 0xFFFFu) | ((v1.w & 0xFFFFu) << 16));
        const uint4 alw = make_uint4(
            (v0.x >> 16) | (v0.y & 0xFFFF0000u), (v0.z >> 16) | (v0.w & 0xFFFF0000u),
            (v1.x >> 16) | (v1.y & 0xFFFF0000u), (v1.z >> 16) | (v1.w & 0xFFFF0000u));
        short8 ah = __builtin_bit_cast(short8, ahw);
        short8 al = __builtin_bit_cast(short8, alw);
        #pragma unroll
        for (int nf = 0; nf < 8; ++nf) {
            const int bo = (nf * 16 + cb) * AP + rg * 8;
            short8 bh = *reinterpret_cast<const short8*>(&wt1h[bo]);
            short8 bl = *reinterpret_cast<const short8*>(&wt1l[bo]);
            acc1[nf] = __builtin_amdgcn_mfma_f32_16x16x32_bf16(ah, bh, acc1[nf], 0, 0, 0);
            acc1[nf] = __builtin_amdgcn_mfma_f32_16x16x32_bf16(al, bh, acc1[nf], 0, 0, 0);
            acc1[nf] = __builtin_amdgcn_mfma_f32_16x16x32_bf16(ah, bl, acc1[nf], 0, 0, 0);
        }
    }
    __syncthreads();     // es/wt1 reads done; z1 overlays
    unsigned short* z1h = reinterpret_cast<unsigned short*>(poolb);
    unsigned short* z1l = reinterpret_cast<unsigned short*>(poolb + 17408);
    unsigned short* w2h = reinterpret_cast<unsigned short*>(poolb + 34816);
    unsigned short* w2l = reinterpret_cast<unsigned short*>(poolb + 39936);
    #pragma unroll
    for (int r = 0; r < 4; ++r) {
        const int row = w * 16 + rg * 4 + r;
        #pragma unroll
        for (int nf = 0; nf < 8; ++nf) {
            float v = gelu_exact(acc1[nf][r] + b1[nf * 16 + cb]);
            unsigned short hi, lo;
            split2(v, hi, lo);
            z1h[row * 136 + nf * 16 + cb] = hi;
            z1l[row * 136 + nf * 16 + cb] = lo;
        }
    }

    // ---- layer 2: K=128 in 4 chunks of 32, N=64
    f32x4 acc2[4];
    #pragma unroll
    for (int nf = 0; nf < 4; ++nf) acc2[nf] = f32x4{0.f, 0.f, 0.f, 0.f};

    for (int kc = 0; kc < 4; ++kc) {
        __syncthreads();
        {   // stage W2 chunk (64 n x 32 k) hi/lo: exactly 256 units
            const int n = tid >> 2, q = tid & 3;
            const size_t so = (size_t)n * 128 + kc * 32 + q * 8;
            *reinterpret_cast<ush8*>(&w2h[n * AP + q * 8]) =
                *reinterpret_cast<const ush8*>(W2Th + so);
            *reinterpret_cast<ush8*>(&w2l[n * AP + q * 8]) =
                *reinterpret_cast<const ush8*>(W2Tl + so);
        }
        __syncthreads();
        const int ao = (w * 16 + cb) * 136 + kc * 32 + rg * 8;
        short8 ah = *reinterpret_cast<const short8*>(&z1h[ao]);
        short8 al = *reinterpret_cast<const short8*>(&z1l[ao]);
        #pragma unroll
        for (int nf = 0; nf < 4; ++nf) {
            const int bo = (nf * 16 + cb) * AP + rg * 8;
            short8 bh = *reinterpret_cast<const short8*>(&w2h[bo]);
            short8 bl = *reinterpret_cast<const short8*>(&w2l[bo]);
            acc2[nf] = __builtin_amdgcn_mfma_f32_16x16x32_bf16(ah, bh, acc2[nf], 0, 0, 0);
            acc2[nf] = __builtin_amdgcn_mfma_f32_16x16x32_bf16(al, bh, acc2[nf], 0, 0, 0);
            acc2[nf] = __builtin_amdgcn_mfma_f32_16x16x32_bf16(ah, bl, acc2[nf], 0, 0, 0);
        }
    }
    __syncthreads();     // z1/w2 reads done; z2f overlays
    float* z2f = reinterpret_cast<float*>(poolb);   // 64 x 68 f32
    #pragma unroll
    for (int r = 0; r < 4; ++r) {
        const int row = w * 16 + rg * 4 + r;
        #pragma unroll
        for (int nf = 0; nf < 4; ++nf)
            z2f[row * 68 + nf * 16 + cb] = gelu_exact(acc2[nf][r] + b2[nf * 16 + cb]);
    }
    __syncthreads();

    // ---- layer 3: dot + sigmoid; flag borderline
    if (tid < 64) {
        const int t = t0 + tid;
        if (t < kT) {
            float s = 0.f;
            #pragma unroll 8
            for (int k = 0; k < 64; ++k) s = fmaf(z2f[tid * 68 + k], W3[k], s);
            const float p = 1.f / (1.f + expf(-(s + b3[0])));
            out[(size_t)b * kS + t + kW] = p;
            out[(size_t)kB * kS + (size_t)b * kS + t + kW] = (p > 0.5f) ? 1.f : 0.f;
            if (fabsf(p - 0.5f) < kMargin) {
                int idx = atomicAdd(fcnt, 1);
                if (idx < FCAP) flist[idx] = ((unsigned)b << 16) | (unsigned)t;
            }
        }
    }
}

// ================= fix2: full fp32 recompute per flagged position =================
__global__ __launch_bounds__(256, 4)
void fix2_kernel(const float* __restrict__ x, const float* __restrict__ Wenc,
                 const float* __restrict__ benc, const float* __restrict__ gma,
                 const float* __restrict__ bta, const float* __restrict__ W1,
                 const float* __restrict__ b1, const float* __restrict__ W2,
                 const float* __restrict__ b2, const float* __restrict__ W3,
                 const float* __restrict__ b3, const int* __restrict__ fcnt,
                 const unsigned* __restrict__ flist, float* __restrict__ out)
{
    __shared__ float xw[1280];
    __shared__ float es[256];
    __shared__ float z1s[128];
    __shared__ float z2s[64];
    __shared__ float wred[4];

    const int tid = threadIdx.x;
    int n = *fcnt; if (n > FCAP) n = FCAP;

    for (int i = blockIdx.x; i < n; i += gridDim.x) {
        const unsigned e = flist[i];
        const int b = (int)(e >> 16), t = (int)(e & 0xFFFF);
        __syncthreads();
        for (int j = tid; j < 320; j += 256) {
            int r = (j >= 160) ? 1 : 0, u = j - r * 160;
            const float4 v = *reinterpret_cast<const float4*>(
                x + ((size_t)b * kS + t + r * kW) * kI + u * 4);
            *reinterpret_cast<float4*>(&xw[r * 640 + u * 4]) = v;
        }
        __syncthreads();
        const int r = tid >> 7, c = tid & 127;
        float h = 0.f;
        const float* xr = &xw[r * 640];
        #pragma unroll 16
        for (int k = 0; k < 640; ++k) h = fmaf(xr[k], Wenc[(size_t)k * kH + c], h);
        h += benc[c];
        float s = h;
        #pragma unroll
        for (int m = 1; m < 64; m <<= 1) s += __shfl_xor(s, m, 64);
        if ((tid & 63) == 0) wred[tid >> 6] = s;
        __syncthreads();
        const float mu = (wred[r * 2] + wred[r * 2 + 1]) * (1.f / 128.f);
        const float d = h - mu;
        float s2 = d * d;
        #pragma unroll
        for (int m = 1; m < 64; m <<= 1) s2 += __shfl_xor(s2, m, 64);
        __syncthreads();
        if ((tid & 63) == 0) wred[tid >> 6] = s2;
        __syncthreads();
        const float var = (wred[r * 2] + wred[r * 2 + 1]) * (1.f / 128.f);
        es[tid] = gelu_exact(d * (1.f / sqrtf(var + kEps)) * gma[c] + bta[c]);
        __syncthreads();
        if (tid < kH) {
            float z = 0.f;
            #pragma unroll 16
            for (int k = 0; k < 256; ++k) z = fmaf(es[k], W1[(size_t)k * kH + tid], z);
            z1s[tid] = gelu_exact(z + b1[tid]);
        }
        __syncthreads();
        if (tid < 64) {
            float z = 0.f;
            #pragma unroll 16
            for (int k = 0; k < kH; ++k) z = fmaf(z1s[k], W2[(size_t)k * 64 + tid], z);
            z2s[tid] = gelu_exact(z + b2[tid]);
        }
        __syncthreads();
        if (tid < 64) {
            float s3 = z2s[tid] * W3[tid];
            #pragma unroll
            for (int m = 1; m < 64; m <<= 1) s3 += __shfl_xor(s3, m, 64);
            if (tid == 0) {
                const float p = 1.f / (1.f + expf(-(s3 + b3[0])));
                out[(size_t)b * kS + t + kW] = p;
                out[(size_t)kB * kS + (size_t)b * kS + t + kW] = (p > 0.5f) ? 1.f : 0.f;
            }
        }
        __syncthreads();
    }
}

}  // namespace

extern "C" void kernel_launch(void* const* d_in, const int* in_sizes, int n_in,
                              void* d_out, int out_size, void* d_ws, size_t ws_size,
                              hipStream_t stream)
{
    const float* x    = (const float*)d_in[0];
    const float* Wenc = (const float*)d_in[1];
    const float* benc = (const float*)d_in[2];
    const float* gma  = (const float*)d_in[3];
    const float* bta  = (const float*)d_in[4];
    const float* W1   = (const float*)d_in[5];
    const float* b1   = (const float*)d_in[6];
    const float* W2   = (const float*)d_in[7];
    const float* b2   = (const float*)d_in[8];
    const float* W3   = (const float*)d_in[9];
    const float* b3   = (const float*)d_in[10];
    float* out = (float*)d_out;

    char* ws = (char*)d_ws;
    unsigned* encp        = (unsigned*)(ws + ENCP_OFF);
    unsigned short* WeTh  = (unsigned short*)(ws + WETH_OFF);
    unsigned short* WeTl  = (unsigned short*)(ws + WETL_OFF);
    unsigned short* W1Th  = (unsigned short*)(ws + W1TH_OFF);
    unsigned short* W1Tl  = (unsigned short*)(ws + W1TL_OFF);
    unsigned short* W2Th  = (unsigned short*)(ws + W2TH_OFF);
    unsigned short* W2Tl  = (unsigned short*)(ws + W2TL_OFF);
    int* fcnt             = (int*)(ws + FC_OFF);
    unsigned* flist       = (unsigned*)(ws + FL_OFF);

    hipMemsetAsync(d_out, 0, (size_t)out_size * sizeof(float), stream);
    hipMemsetAsync(fcnt, 0, 64, stream);

    prep_kernel<<<256, 256, 0, stream>>>(Wenc, W1, W2, WeTh, WeTl, W1Th, W1Tl, W2Th, W2Tl);
    enc_kernel<<<dim3(8, kB), 512, 0, stream>>>(x, WeTh, WeTl, benc, gma, bta, encp);
    cmp_kernel<<<dim3(32, kB), 256, 0, stream>>>(encp, W1Th, W1Tl, b1, W2Th, W2Tl, b2,
                                                 W3, b3, out, fcnt, flist);
    fix2_kernel<<<4096, 256, 0, stream>>>(x, Wenc, benc, gma, bta, W1, b1, W2, b2, W3, b3,
                                          fcnt, flist, out);
}

// Round 15
// 133.762 us; speedup vs baseline: 1.0812x; 1.0812x over previous
//
#include <hip/hip_runtime.h>
#include <hip/hip_bf16.h>
#include <math.h>

namespace {

constexpr int kB = 32;
constexpr int kS = 2048;
constexpr int kI = 32;
constexpr int kW = 20;
constexpr int kH = 128;
constexpr int kNwin = kS - kW + 1;   // 2029
constexpr int kT = kS - 2 * kW;      // 2008
constexpr float kEps = 1e-5f;
constexpr int FCAP = 4096;
constexpr float kMargin = 1e-3f;

typedef __attribute__((ext_vector_type(8))) short short8;          // 8 bf16
typedef __attribute__((ext_vector_type(8))) unsigned short ush8;   // 16B unit
typedef __attribute__((ext_vector_type(4))) float f32x4;

// async global->LDS DMA, 16B per lane; dest = uniform base + lane*16 (linear)
#define GLD16(SRC, DST)                                                          \
    __builtin_amdgcn_global_load_lds(                                            \
        (const __attribute__((address_space(1))) unsigned*)(const void*)(SRC),   \
        (__attribute__((address_space(3))) unsigned*)(void*)(DST), 16, 0, 0)

__device__ __forceinline__ unsigned short f2bf(float f) {
    unsigned u = __builtin_bit_cast(unsigned, f);
    u += 0x7FFFu + ((u >> 16) & 1u);
    return (unsigned short)(u >> 16);
}
__device__ __forceinline__ float bf2f(unsigned short h) {
    unsigned u = ((unsigned)h) << 16;
    return __builtin_bit_cast(float, u);
}
__device__ __forceinline__ void split2(float v, unsigned short& hi, unsigned short& lo) {
    hi = f2bf(v);
    lo = f2bf(v - bf2f(hi));
}
__device__ __forceinline__ float gelu_exact(float v) {
    return 0.5f * v * (1.0f + erff(v * 0.70710678118654752440f));
}

// ---- workspace layout (bytes) ----
constexpr size_t ENCP_OFF = 0;                        // packed enc u32: 33.5 MB
constexpr size_t WETH_OFF = 33554432;                 // WencT hi [128][640]
constexpr size_t WETL_OFF = WETH_OFF + 163840;
constexpr size_t W1TH_OFF = WETL_OFF + 163840;        // W1T hi [128][256]
constexpr size_t W1TL_OFF = W1TH_OFF + 65536;
constexpr size_t W2TH_OFF = W1TL_OFF + 65536;         // W2T hi [64][128]
constexpr size_t W2TL_OFF = W2TH_OFF + 16384;
constexpr size_t FC_OFF   = W2TL_OFF + 16384;
constexpr size_t FL_OFF   = FC_OFF + 64;

// ================= prep: W transposes + hi/lo splits =================
__global__ void prep_kernel(const float* __restrict__ Wenc, const float* __restrict__ W1,
                            const float* __restrict__ W2,
                            unsigned short* __restrict__ WeTh, unsigned short* __restrict__ WeTl,
                            unsigned short* __restrict__ W1Th, unsigned short* __restrict__ W1Tl,
                            unsigned short* __restrict__ W2Th, unsigned short* __restrict__ W2Tl)
{
    const int tid = blockIdx.x * blockDim.x + threadIdx.x;
    const int nth = gridDim.x * blockDim.x;
    for (int i = tid; i < kH * 640; i += nth) {
        int n = i / 640, k = i - n * 640;
        split2(Wenc[(size_t)k * kH + n], WeTh[i], WeTl[i]);
    }
    for (int i = tid; i < kH * 256; i += nth) {
        int n = i >> 8, k = i & 255;
        split2(W1[(size_t)k * kH + n], W1Th[i], W1Tl[i]);
    }
    for (int i = tid; i < 64 * kH; i += nth) {
        int n = i >> 7, k = i & 127;
        split2(W2[(size_t)k * 64 + n], W2Th[i], W2Tl[i]);
    }
}

// ================= encoder: split-bf16 MFMA + LN + GELU (512 thr, 2D wave tile) =================
// 8 waves; wave (wr = w>>1, wc = w&1): rows wr*32..+31, cols wc*64..+63.
// W tiles: LINEAR LDS [n][k-octet] (pitch 32 ush), filled via global_load_lds.
constexpr int AP = 40;    // x LDS pitch in ushorts (80B)

__global__ __launch_bounds__(512, 4)
void enc_kernel(const float* __restrict__ x,
                const unsigned short* __restrict__ WeTh, const unsigned short* __restrict__ WeTl,
                const float* __restrict__ benc, const float* __restrict__ gma,
                const float* __restrict__ bta, unsigned* __restrict__ encp)
{
    __shared__ unsigned short xsh[147 * AP];     // 5880
    __shared__ unsigned short xsl[147 * AP];
    __shared__ unsigned short wth[128 * 32];     // 4096 ush, linear
    __shared__ unsigned short wtl[128 * 32];
    __shared__ float red[2][128][2];             // LN partials [stat][row][wc]

    const int tid = threadIdx.x, b = blockIdx.y, t0 = blockIdx.x * 128;
    const int l = tid & 63, w = tid >> 6;
    const int wr = w >> 1, wc = w & 1;
    const int cb = l & 15, rg = l >> 4;

    // stage x rows t0..t0+146 (f32 -> hi/lo bf16)
    const float4* x4 = reinterpret_cast<const float4*>(x + (size_t)b * kS * kI);
    for (int i = tid; i < 147 * 8; i += 512) {
        int r = i >> 3, q = i & 7;
        int gr = t0 + r; if (gr > kS - 1) gr = kS - 1;
        float4 v = x4[gr * 8 + q];
        unsigned short h0, h1, h2, h3, l0, l1, l2, l3;
        split2(v.x, h0, l0); split2(v.y, h1, l1); split2(v.z, h2, l2); split2(v.w, h3, l3);
        *reinterpret_cast<uint2*>(&xsh[r * AP + q * 4]) =
            make_uint2((unsigned)h0 | ((unsigned)h1 << 16), (unsigned)h2 | ((unsigned)h3 << 16));
        *reinterpret_cast<uint2*>(&xsl[r * AP + q * 4]) =
            make_uint2((unsigned)l0 | ((unsigned)l1 << 16), (unsigned)l2 | ((unsigned)l3 << 16));
    }

    f32x4 acc[2][4];
    #pragma unroll
    for (int mi = 0; mi < 2; ++mi)
        #pragma unroll
        for (int nf = 0; nf < 4; ++nf) acc[mi][nf] = f32x4{0.f, 0.f, 0.f, 0.f};

    // W DMA addressing: wave w fills segment w (1KB): n = 16w + (l>>2), ko = l&3
    const int wn = 16 * w + (l >> 2), wko = l & 3;

    for (int kc = 0; kc < 20; ++kc) {            // K = 640 in chunks of 32
        __syncthreads();                         // prior reads done before DMA overwrite
        GLD16(WeTh + (size_t)wn * 640 + kc * 32 + wko * 8, &wth[w * 512]);
        GLD16(WeTl + (size_t)wn * 640 + kc * 32 + wko * 8, &wtl[w * 512]);
        __syncthreads();                         // vmcnt(0) drained -> W tile ready
        const int a0o = (wr * 32 + cb + kc) * AP + rg * 8;
        short8 a0h = *reinterpret_cast<const short8*>(&xsh[a0o]);
        short8 a0l = *reinterpret_cast<const short8*>(&xsl[a0o]);
        short8 a1h = *reinterpret_cast<const short8*>(&xsh[a0o + 16 * AP]);
        short8 a1l = *reinterpret_cast<const short8*>(&xsl[a0o + 16 * AP]);
        #pragma unroll
        for (int nf = 0; nf < 4; ++nf) {
            const int bo = (wc * 64 + nf * 16 + cb) * 32 + rg * 8;   // linear pitch-32
            short8 bh = *reinterpret_cast<const short8*>(&wth[bo]);
            short8 bl = *reinterpret_cast<const short8*>(&wtl[bo]);
            acc[0][nf] = __builtin_amdgcn_mfma_f32_16x16x32_bf16(a0h, bh, acc[0][nf], 0, 0, 0);
            acc[0][nf] = __builtin_amdgcn_mfma_f32_16x16x32_bf16(a0l, bh, acc[0][nf], 0, 0, 0);
            acc[0][nf] = __builtin_amdgcn_mfma_f32_16x16x32_bf16(a0h, bl, acc[0][nf], 0, 0, 0);
            acc[1][nf] = __builtin_amdgcn_mfma_f32_16x16x32_bf16(a1h, bh, acc[1][nf], 0, 0, 0);
            acc[1][nf] = __builtin_amdgcn_mfma_f32_16x16x32_bf16(a1l, bh, acc[1][nf], 0, 0, 0);
            acc[1][nf] = __builtin_amdgcn_mfma_f32_16x16x32_bf16(a1h, bl, acc[1][nf], 0, 0, 0);
        }
    }

    // epilogue: C/D col = lane&15, row = (lane>>4)*4 + reg
    float bv[4], gv[4], btv[4];
    #pragma unroll
    for (int nf = 0; nf < 4; ++nf) {
        const int col = wc * 64 + nf * 16 + cb;
        bv[nf] = benc[col]; gv[nf] = gma[col]; btv[nf] = bta[col];
    }
    float h[2][4][4];
    #pragma unroll
    for (int mi = 0; mi < 2; ++mi)
        #pragma unroll
        for (int r = 0; r < 4; ++r) {
            float s = 0.f;
            #pragma unroll
            for (int nf = 0; nf < 4; ++nf) {
                h[mi][r][nf] = acc[mi][nf][r] + bv[nf];
                s += h[mi][r][nf];
            }
            s += __shfl_xor(s, 1); s += __shfl_xor(s, 2);
            s += __shfl_xor(s, 4); s += __shfl_xor(s, 8);
            if (cb == 0) red[0][wr * 32 + mi * 16 + rg * 4 + r][wc] = s;
        }
    __syncthreads();
    #pragma unroll
    for (int mi = 0; mi < 2; ++mi)
        #pragma unroll
        for (int r = 0; r < 4; ++r) {
            const int rl = wr * 32 + mi * 16 + rg * 4 + r;
            const float mu = (red[0][rl][0] + red[0][rl][1]) * (1.f / 128.f);
            float s2 = 0.f;
            #pragma unroll
            for (int nf = 0; nf < 4; ++nf) {
                h[mi][r][nf] -= mu;
                s2 += h[mi][r][nf] * h[mi][r][nf];
            }
            s2 += __shfl_xor(s2, 1); s2 += __shfl_xor(s2, 2);
            s2 += __shfl_xor(s2, 4); s2 += __shfl_xor(s2, 8);
            if (cb == 0) red[1][rl][wc] = s2;
        }
    __syncthreads();
    #pragma unroll
    for (int mi = 0; mi < 2; ++mi)
        #pragma unroll
        for (int r = 0; r < 4; ++r) {
            const int rl = wr * 32 + mi * 16 + rg * 4 + r;
            const int t = t0 + rl;
            const float var = (red[1][rl][0] + red[1][rl][1]) * (1.f / 128.f);
            const float rstd = 1.f / sqrtf(var + kEps);
            if (t < kNwin) {
                unsigned* dst = encp + ((size_t)(b * kS + t)) * kH;
                #pragma unroll
                for (int nf = 0; nf < 4; ++nf) {
                    float v = gelu_exact(h[mi][r][nf] * rstd * gv[nf] + btv[nf]);
                    unsigned short hi, lo;
                    split2(v, hi, lo);
                    dst[wc * 64 + nf * 16 + cb] = (unsigned)hi | ((unsigned)lo << 16);
                }
            }
        }
}

// ================= comparator (512 thr, 2D wave tile): L1 16r x 64c, L2 16r x 32c =================
// pool (ush): phase1: esh@0 (64*72=4608) | esl@4608 | wt1h@9216 (8192, linear [n][ko]) |
//             wt1l@17408 (8192) -> ends 25600
//             phase2: z1h@0 (64*136=8704) | z1l@8704 | w2h@17408 (4096) | w2l@21504 -> 25600
//             phase3: z2f f32 @0 (64*68)
constexpr int EPP = 72;

__global__ __launch_bounds__(512, 4)
void cmp_kernel(const unsigned* __restrict__ encp,
                const unsigned short* __restrict__ W1Th, const unsigned short* __restrict__ W1Tl,
                const float* __restrict__ b1,
                const unsigned short* __restrict__ W2Th, const unsigned short* __restrict__ W2Tl,
                const float* __restrict__ b2, const float* __restrict__ W3,
                const float* __restrict__ b3, float* __restrict__ out,
                int* __restrict__ fcnt, unsigned* __restrict__ flist)
{
    __shared__ __align__(16) unsigned short pool[25600];   // 51.2 KB
    __shared__ float prm[192];

    unsigned short* esh  = pool;
    unsigned short* esl  = pool + 4608;
    unsigned short* wt1h = pool + 9216;
    unsigned short* wt1l = pool + 17408;

    const int tid = threadIdx.x, b = blockIdx.y, t0 = blockIdx.x * 64;
    const int l = tid & 63, w = tid >> 6;
    const int wr = w >> 1, wc = w & 1;
    const int cb = l & 15, rg = l >> 4;

    if (tid < 128) prm[tid] = b1[tid];
    else if (tid < 192) prm[tid] = b2[tid - 128];

    // ---- layer 1: A[t][k] = enc[t + (k<128?0:20)][k&127], K=256 in 4 chunks of 64
    f32x4 acc1[4];
    #pragma unroll
    for (int nf = 0; nf < 4; ++nf) acc1[nf] = f32x4{0.f, 0.f, 0.f, 0.f};

    // W1 DMA: 16 segments per chunk; wave w fills segs 2w, 2w+1:
    //   seg s: n = 8s + (l>>3), ko = l&7; LDS base = 512*s ush
    const int n1 = 16 * w + (l >> 3), n2 = n1 + 8, ko8 = l & 7;

    for (int kc = 0; kc < 4; ++kc) {
        const int ro = (kc < 2) ? 0 : kW, co = (kc & 1) * 64;
        __syncthreads();
        GLD16(W1Th + (size_t)n1 * 256 + kc * 64 + ko8 * 8, &wt1h[w * 1024]);
        GLD16(W1Th + (size_t)n2 * 256 + kc * 64 + ko8 * 8, &wt1h[w * 1024 + 512]);
        GLD16(W1Tl + (size_t)n1 * 256 + kc * 64 + ko8 * 8, &wt1l[w * 1024]);
        GLD16(W1Tl + (size_t)n2 * 256 + kc * 64 + ko8 * 8, &wt1l[w * 1024 + 512]);
        {   // stage enc slice: 64 rows x 64 packed u32 -> hi/lo (8 thr/row, 8 u32 each)
            const int r = tid >> 3, qq = tid & 7;
            int gr = t0 + ro + r; if (gr > kNwin - 1) gr = kNwin - 1;
            const unsigned* src = encp + ((size_t)(b * kS + gr)) * kH + co + qq * 8;
            const uint4 v0 = *reinterpret_cast<const uint4*>(src);
            const uint4 v1 = *reinterpret_cast<const uint4*>(src + 4);
            *reinterpret_cast<uint2*>(&esh[r * EPP + qq * 8]) =
                make_uint2((v0.x & 0xFFFFu) | ((v0.y & 0xFFFFu) << 16),
                           (v0.z & 0xFFFFu) | ((v0.w & 0xFFFFu) << 16));
            *reinterpret_cast<uint2*>(&esh[r * EPP + qq * 8 + 4]) =
                make_uint2((v1.x & 0xFFFFu) | ((v1.y & 0xFFFFu) << 16),
                           (v1.z & 0xFFFFu) | ((v1.w & 0xFFFFu) << 16));
            *reinterpret_cast<uint2*>(&esl[r * EPP + qq * 8]) =
                make_uint2((v0.x >> 16) | (v0.y & 0xFFFF0000u),
                           (v0.z >> 16) | (v0.w & 0xFFFF0000u));
            *reinterpret_cast<uint2*>(&esl[r * EPP + qq * 8 + 4]) =
                make_uint2((v1.x >> 16) | (v1.y & 0xFFFF0000u),
                           (v1.z >> 16) | (v1.w & 0xFFFF0000u));
        }
        __syncthreads();
        #pragma unroll
        for (int ks = 0; ks < 2; ++ks) {
            const int ao = (wr * 16 + cb) * EPP + ks * 32 + rg * 8;
            short8 ah = *reinterpret_cast<const short8*>(&esh[ao]);
            short8 al = *reinterpret_cast<const short8*>(&esl[ao]);
            #pragma unroll
            for (int nf = 0; nf < 4; ++nf) {
                const int bo = (wc * 64 + nf * 16 + cb) * 64 + ks * 32 + rg * 8;
                short8 bh = *reinterpret_cast<const short8*>(&wt1h[bo]);
                short8 bl = *reinterpret_cast<const short8*>(&wt1l[bo]);
                acc1[nf] = __builtin_amdgcn_mfma_f32_16x16x32_bf16(ah, bh, acc1[nf], 0, 0, 0);
                acc1[nf] = __builtin_amdgcn_mfma_f32_16x16x32_bf16(al, bh, acc1[nf], 0, 0, 0);
                acc1[nf] = __builtin_amdgcn_mfma_f32_16x16x32_bf16(ah, bl, acc1[nf], 0, 0, 0);
            }
        }
    }
    __syncthreads();     // all es/wt1 reads done; z1 overlays
    unsigned short* z1h = pool;
    unsigned short* z1l = pool + 8704;
    unsigned short* w2h = pool + 17408;
    unsigned short* w2l = pool + 21504;
    #pragma unroll
    for (int r = 0; r < 4; ++r) {
        const int row = wr * 16 + rg * 4 + r;
        #pragma unroll
        for (int nf = 0; nf < 4; ++nf) {
            const int col = wc * 64 + nf * 16 + cb;
            float v = gelu_exact(acc1[nf][r] + prm[col]);
            unsigned short hi, lo;
            split2(v, hi, lo);
            z1h[row * 136 + col] = hi;
            z1l[row * 136 + col] = lo;
        }
    }

    // ---- layer 2: K=128 in 2 chunks of 64, N=64; wave tile 16r x 32c
    f32x4 acc2[2];
    #pragma unroll
    for (int nf = 0; nf < 2; ++nf) acc2[nf] = f32x4{0.f, 0.f, 0.f, 0.f};

    const int n2b = 8 * w + (l >> 3);   // W2 DMA: wave w seg w

    for (int kc2 = 0; kc2 < 2; ++kc2) {
        __syncthreads();
        GLD16(W2Th + (size_t)n2b * 128 + kc2 * 64 + ko8 * 8, &w2h[w * 512]);
        GLD16(W2Tl + (size_t)n2b * 128 + kc2 * 64 + ko8 * 8, &w2l[w * 512]);
        __syncthreads();
        #pragma unroll
        for (int ks = 0; ks < 2; ++ks) {
            const int ao = (wr * 16 + cb) * 136 + kc2 * 64 + ks * 32 + rg * 8;
            short8 ah = *reinterpret_cast<const short8*>(&z1h[ao]);
            short8 al = *reinterpret_cast<const short8*>(&z1l[ao]);
            #pragma unroll
            for (int nf = 0; nf < 2; ++nf) {
                const int bo = (wc * 32 + nf * 16 + cb) * 64 + ks * 32 + rg * 8;
                short8 bh = *reinterpret_cast<const short8*>(&w2h[bo]);
                short8 bl = *reinterpret_cast<const short8*>(&w2l[bo]);
                acc2[nf] = __builtin_amdgcn_mfma_f32_16x16x32_bf16(ah, bh, acc2[nf], 0, 0, 0);
                acc2[nf] = __builtin_amdgcn_mfma_f32_16x16x32_bf16(al, bh, acc2[nf], 0, 0, 0);
                acc2[nf] = __builtin_amdgcn_mfma_f32_16x16x32_bf16(ah, bl, acc2[nf], 0, 0, 0);
            }
        }
    }
    __syncthreads();     // z1/w2 reads done; z2f overlays
    float* z2f = reinterpret_cast<float*>(pool);   // 64 x 68 f32
    #pragma unroll
    for (int r = 0; r < 4; ++r) {
        const int row = wr * 16 + rg * 4 + r;
        #pragma unroll
        for (int nf = 0; nf < 2; ++nf) {
            const int col = wc * 32 + nf * 16 + cb;
            z2f[row * 68 + col] = gelu_exact(acc2[nf][r] + prm[128 + col]);
        }
    }
    __syncthreads();

    // ---- layer 3: dot + sigmoid; flag borderline
    if (tid < 64) {
        const int t = t0 + tid;
        if (t < kT) {
            float s = 0.f;
            #pragma unroll 8
            for (int k = 0; k < 64; ++k) s = fmaf(z2f[tid * 68 + k], W3[k], s);
            const float p = 1.f / (1.f + expf(-(s + b3[0])));
            out[(size_t)b * kS + t + kW] = p;
            out[(size_t)kB * kS + (size_t)b * kS + t + kW] = (p > 0.5f) ? 1.f : 0.f;
            if (fabsf(p - 0.5f) < kMargin) {
                int idx = atomicAdd(fcnt, 1);
                if (idx < FCAP) flist[idx] = ((unsigned)b << 16) | (unsigned)t;
            }
        }
    }
}

// ================= fix2: full fp32 recompute per flagged position =================
__global__ __launch_bounds__(256, 4)
void fix2_kernel(const float* __restrict__ x, const float* __restrict__ Wenc,
                 const float* __restrict__ benc, const float* __restrict__ gma,
                 const float* __restrict__ bta, const float* __restrict__ W1,
                 const float* __restrict__ b1, const float* __restrict__ W2,
                 const float* __restrict__ b2, const float* __restrict__ W3,
                 const float* __restrict__ b3, const int* __restrict__ fcnt,
                 const unsigned* __restrict__ flist, float* __restrict__ out)
{
    __shared__ float xw[1280];
    __shared__ float es[256];
    __shared__ float z1s[128];
    __shared__ float z2s[64];
    __shared__ float wred[4];

    const int tid = threadIdx.x;
    int n = *fcnt; if (n > FCAP) n = FCAP;

    for (int i = blockIdx.x; i < n; i += gridDim.x) {
        const unsigned e = flist[i];
        const int b = (int)(e >> 16), t = (int)(e & 0xFFFF);
        __syncthreads();
        for (int j = tid; j < 320; j += 256) {
            int r = (j >= 160) ? 1 : 0, u = j - r * 160;
            const float4 v = *reinterpret_cast<const float4*>(
                x + ((size_t)b * kS + t + r * kW) * kI + u * 4);
            *reinterpret_cast<float4*>(&xw[r * 640 + u * 4]) = v;
        }
        __syncthreads();
        const int r = tid >> 7, c = tid & 127;
        float h = 0.f;
        const float* xr = &xw[r * 640];
        #pragma unroll 16
        for (int k = 0; k < 640; ++k) h = fmaf(xr[k], Wenc[(size_t)k * kH + c], h);
        h += benc[c];
        float s = h;
        #pragma unroll
        for (int m = 1; m < 64; m <<= 1) s += __shfl_xor(s, m, 64);
        if ((tid & 63) == 0) wred[tid >> 6] = s;
        __syncthreads();
        const float mu = (wred[r * 2] + wred[r * 2 + 1]) * (1.f / 128.f);
        const float d = h - mu;
        float s2 = d * d;
        #pragma unroll
        for (int m = 1; m < 64; m <<= 1) s2 += __shfl_xor(s2, m, 64);
        __syncthreads();
        if ((tid & 63) == 0) wred[tid >> 6] = s2;
        __syncthreads();
        const float var = (wred[r * 2] + wred[r * 2 + 1]) * (1.f / 128.f);
        es[tid] = gelu_exact(d * (1.f / sqrtf(var + kEps)) * gma[c] + bta[c]);
        __syncthreads();
        if (tid < kH) {
            float z = 0.f;
            #pragma unroll 16
            for (int k = 0; k < 256; ++k) z = fmaf(es[k], W1[(size_t)k * kH + tid], z);
            z1s[tid] = gelu_exact(z + b1[tid]);
        }
        __syncthreads();
        if (tid < 64) {
            float z = 0.f;
            #pragma unroll 16
            for (int k = 0; k < kH; ++k) z = fmaf(z1s[k], W2[(size_t)k * 64 + tid], z);
            z2s[tid] = gelu_exact(z + b2[tid]);
        }
        __syncthreads();
        if (tid < 64) {
            float s3 = z2s[tid] * W3[tid];
            #pragma unroll
            for (int m = 1; m < 64; m <<= 1) s3 += __shfl_xor(s3, m, 64);
            if (tid == 0) {
                const float p = 1.f / (1.f + expf(-(s3 + b3[0])));
                out[(size_t)b * kS + t + kW] = p;
                out[(size_t)kB * kS + (size_t)b * kS + t + kW] = (p > 0.5f) ? 1.f : 0.f;
            }
        }
        __syncthreads();
    }
}

}  // namespace

extern "C" void kernel_launch(void* const* d_in, const int* in_sizes, int n_in,
                              void* d_out, int out_size, void* d_ws, size_t ws_size,
                              hipStream_t stream)
{
    const float* x    = (const float*)d_in[0];
    const float* Wenc = (const float*)d_in[1];
    const float* benc = (const float*)d_in[2];
    const float* gma  = (const float*)d_in[3];
    const float* bta  = (const float*)d_in[4];
    const float* W1   = (const float*)d_in[5];
    const float* b1   = (const float*)d_in[6];
    const float* W2   = (const float*)d_in[7];
    const float* b2   = (const float*)d_in[8];
    const float* W3   = (const float*)d_in[9];
    const float* b3   = (const float*)d_in[10];
    float* out = (float*)d_out;

    char* ws = (char*)d_ws;
    unsigned* encp        = (unsigned*)(ws + ENCP_OFF);
    unsigned short* WeTh  = (unsigned short*)(ws + WETH_OFF);
    unsigned short* WeTl  = (unsigned short*)(ws + WETL_OFF);
    unsigned short* W1Th  = (unsigned short*)(ws + W1TH_OFF);
    unsigned short* W1Tl  = (unsigned short*)(ws + W1TL_OFF);
    unsigned short* W2Th  = (unsigned short*)(ws + W2TH_OFF);
    unsigned short* W2Tl  = (unsigned short*)(ws + W2TL_OFF);
    int* fcnt             = (int*)(ws + FC_OFF);
    unsigned* flist       = (unsigned*)(ws + FL_OFF);

    hipMemsetAsync(d_out, 0, (size_t)out_size * sizeof(float), stream);
    hipMemsetAsync(fcnt, 0, 64, stream);

    prep_kernel<<<256, 256, 0, stream>>>(Wenc, W1, W2, WeTh, WeTl, W1Th, W1Tl, W2Th, W2Tl);
    enc_kernel<<<dim3(16, kB), 512, 0, stream>>>(x, WeTh, WeTl, benc, gma, bta, encp);
    cmp_kernel<<<dim3(32, kB), 512, 0, stream>>>(encp, W1Th, W1Tl, b1, W2Th, W2Tl, b2,
                                                 W3, b3, out, fcnt, flist);
    fix2_kernel<<<4096, 256, 0, stream>>>(x, Wenc, benc, gma, bta, W1, b1, W2, b2, W3, b3,
                                          fcnt, flist, out);
}

// Round 16
// 130.670 us; speedup vs baseline: 1.1068x; 1.0237x over previous
//
#include <hip/hip_runtime.h>
#include <hip/hip_bf16.h>
#include <math.h>

namespace {

constexpr int kB = 32;
constexpr int kS = 2048;
constexpr int kI = 32;
constexpr int kW = 20;
constexpr int kH = 128;
constexpr int kNwin = kS - kW + 1;   // 2029
constexpr int kT = kS - 2 * kW;      // 2008
constexpr float kEps = 1e-5f;
constexpr int FCAP = 4096;
constexpr float kMargin = 1e-3f;

typedef __attribute__((ext_vector_type(8))) short short8;          // 8 bf16
typedef __attribute__((ext_vector_type(8))) unsigned short ush8;   // 16B unit
typedef __attribute__((ext_vector_type(4))) float f32x4;

// async global->LDS DMA, 16B per lane; dest = uniform base + lane*16 (linear)
#define GLD16(SRC, DST)                                                          \
    __builtin_amdgcn_global_load_lds(                                            \
        (const __attribute__((address_space(1))) unsigned*)(const void*)(SRC),   \
        (__attribute__((address_space(3))) unsigned*)(void*)(DST), 16, 0, 0)

__device__ __forceinline__ unsigned short f2bf(float f) {
    unsigned u = __builtin_bit_cast(unsigned, f);
    u += 0x7FFFu + ((u >> 16) & 1u);
    return (unsigned short)(u >> 16);
}
__device__ __forceinline__ float bf2f(unsigned short h) {
    unsigned u = ((unsigned)h) << 16;
    return __builtin_bit_cast(float, u);
}
__device__ __forceinline__ void split2(float v, unsigned short& hi, unsigned short& lo) {
    hi = f2bf(v);
    lo = f2bf(v - bf2f(hi));
}
__device__ __forceinline__ float gelu_exact(float v) {
    return 0.5f * v * (1.0f + erff(v * 0.70710678118654752440f));
}

// ---- workspace layout (bytes) ----
constexpr size_t ENCP_OFF = 0;                        // packed enc u32: 33.5 MB
constexpr size_t WETH_OFF = 33554432;                 // WencF hi, frag-major [20][4][128][8]
constexpr size_t WETL_OFF = WETH_OFF + 163840;
constexpr size_t W1TH_OFF = WETL_OFF + 163840;        // W1F hi, frag-major [4][2][4][128][8]
constexpr size_t W1TL_OFF = W1TH_OFF + 65536;
constexpr size_t W2TH_OFF = W1TL_OFF + 65536;         // W2F hi, frag-major [2][2][4][64][8]
constexpr size_t W2TL_OFF = W2TH_OFF + 16384;
constexpr size_t FC_OFF   = W2TL_OFF + 16384;
constexpr size_t FL_OFF   = FC_OFF + 64;

// ================= prep: frag-major W layouts + hi/lo splits =================
__global__ void prep_kernel(const float* __restrict__ Wenc, const float* __restrict__ W1,
                            const float* __restrict__ W2,
                            unsigned short* __restrict__ WeFh, unsigned short* __restrict__ WeFl,
                            unsigned short* __restrict__ W1Fh, unsigned short* __restrict__ W1Fl,
                            unsigned short* __restrict__ W2Fh, unsigned short* __restrict__ W2Fl)
{
    const int tid = blockIdx.x * blockDim.x + threadIdx.x;
    const int nth = gridDim.x * blockDim.x;
    // WencF: [kc<20][rg<4][n<128][j<8], k = kc*32+rg*8+j
    for (int i = tid; i < 20 * 4 * 128 * 8; i += nth) {
        int j = i & 7, n = (i >> 3) & 127, rg = (i >> 10) & 3, kc = i >> 12;
        int k = kc * 32 + rg * 8 + j;
        split2(Wenc[(size_t)k * kH + n], WeFh[i], WeFl[i]);
    }
    // W1F: [kc<4][ks<2][rg<4][n<128][j<8], k = kc*64+ks*32+rg*8+j
    for (int i = tid; i < 4 * 2 * 4 * 128 * 8; i += nth) {
        int j = i & 7, n = (i >> 3) & 127, rg = (i >> 10) & 3, ks = (i >> 12) & 1, kc = i >> 13;
        int k = kc * 64 + ks * 32 + rg * 8 + j;
        split2(W1[(size_t)k * kH + n], W1Fh[i], W1Fl[i]);
    }
    // W2F: [kc2<2][ks<2][rg<4][n<64][j<8], k = kc2*64+ks*32+rg*8+j
    for (int i = tid; i < 2 * 2 * 4 * 64 * 8; i += nth) {
        int j = i & 7, n = (i >> 3) & 63, rg = (i >> 9) & 3, ks = (i >> 11) & 1, kc2 = i >> 12;
        int k = kc2 * 64 + ks * 32 + rg * 8 + j;
        split2(W2[(size_t)k * 64 + n], W2Fh[i], W2Fl[i]);
    }
}

// ================= encoder: split-bf16 MFMA + LN + GELU (512 thr, 2D wave tile) =================
// 8 waves; wave (wr = w>>1, wc = w&1): rows wr*32..+31, cols wc*64..+63.
// W tiles: frag-major LDS [rg][n][8] per K=32 chunk, filled by linear DMA.
constexpr int AP = 40;    // x LDS pitch in ushorts (80B, keeps 16B-aligned b128)

__global__ __launch_bounds__(512, 4)
void enc_kernel(const float* __restrict__ x,
                const unsigned short* __restrict__ WeFh, const unsigned short* __restrict__ WeFl,
                const float* __restrict__ benc, const float* __restrict__ gma,
                const float* __restrict__ bta, unsigned* __restrict__ encp)
{
    __shared__ unsigned short xsh[147 * AP];     // 5880
    __shared__ unsigned short xsl[147 * AP];
    __shared__ unsigned short wth[4096];         // frag-major chunk [rg][n][8]
    __shared__ unsigned short wtl[4096];
    __shared__ float red[2][128][2];             // LN partials [stat][row][wc]

    const int tid = threadIdx.x, b = blockIdx.y, t0 = blockIdx.x * 128;
    const int l = tid & 63, w = tid >> 6;
    const int wr = w >> 1, wc = w & 1;
    const int cb = l & 15, rg = l >> 4;

    // stage x rows t0..t0+146 (f32 -> hi/lo bf16)
    const float4* x4 = reinterpret_cast<const float4*>(x + (size_t)b * kS * kI);
    for (int i = tid; i < 147 * 8; i += 512) {
        int r = i >> 3, q = i & 7;
        int gr = t0 + r; if (gr > kS - 1) gr = kS - 1;
        float4 v = x4[gr * 8 + q];
        unsigned short h0, h1, h2, h3, l0, l1, l2, l3;
        split2(v.x, h0, l0); split2(v.y, h1, l1); split2(v.z, h2, l2); split2(v.w, h3, l3);
        *reinterpret_cast<uint2*>(&xsh[r * AP + q * 4]) =
            make_uint2((unsigned)h0 | ((unsigned)h1 << 16), (unsigned)h2 | ((unsigned)h3 << 16));
        *reinterpret_cast<uint2*>(&xsl[r * AP + q * 4]) =
            make_uint2((unsigned)l0 | ((unsigned)l1 << 16), (unsigned)l2 | ((unsigned)l3 << 16));
    }

    f32x4 acc[2][4];
    #pragma unroll
    for (int mi = 0; mi < 2; ++mi)
        #pragma unroll
        for (int nf = 0; nf < 4; ++nf) acc[mi][nf] = f32x4{0.f, 0.f, 0.f, 0.f};

    for (int kc = 0; kc < 20; ++kc) {            // K = 640 in chunks of 32
        __syncthreads();                         // prior reads done before DMA overwrite
        GLD16(WeFh + (size_t)kc * 4096 + w * 512 + l * 8, &wth[w * 512]);
        GLD16(WeFl + (size_t)kc * 4096 + w * 512 + l * 8, &wtl[w * 512]);
        __syncthreads();                         // DMA drained -> W tile ready
        const int a0o = (wr * 32 + cb + kc) * AP + rg * 8;
        short8 a0h = *reinterpret_cast<const short8*>(&xsh[a0o]);
        short8 a0l = *reinterpret_cast<const short8*>(&xsl[a0o]);
        short8 a1h = *reinterpret_cast<const short8*>(&xsh[a0o + 16 * AP]);
        short8 a1l = *reinterpret_cast<const short8*>(&xsl[a0o + 16 * AP]);
        #pragma unroll
        for (int nf = 0; nf < 4; ++nf) {
            const int bo = rg * 1024 + (wc * 64 + nf * 16 + cb) * 8;   // frag-major: conflict-free
            short8 bh = *reinterpret_cast<const short8*>(&wth[bo]);
            short8 bl = *reinterpret_cast<const short8*>(&wtl[bo]);
            acc[0][nf] = __builtin_amdgcn_mfma_f32_16x16x32_bf16(a0h, bh, acc[0][nf], 0, 0, 0);
            acc[0][nf] = __builtin_amdgcn_mfma_f32_16x16x32_bf16(a0l, bh, acc[0][nf], 0, 0, 0);
            acc[0][nf] = __builtin_amdgcn_mfma_f32_16x16x32_bf16(a0h, bl, acc[0][nf], 0, 0, 0);
            acc[1][nf] = __builtin_amdgcn_mfma_f32_16x16x32_bf16(a1h, bh, acc[1][nf], 0, 0, 0);
            acc[1][nf] = __builtin_amdgcn_mfma_f32_16x16x32_bf16(a1l, bh, acc[1][nf], 0, 0, 0);
            acc[1][nf] = __builtin_amdgcn_mfma_f32_16x16x32_bf16(a1h, bl, acc[1][nf], 0, 0, 0);
        }
    }

    // epilogue: C/D col = lane&15, row = (lane>>4)*4 + reg
    float bv[4], gv[4], btv[4];
    #pragma unroll
    for (int nf = 0; nf < 4; ++nf) {
        const int col = wc * 64 + nf * 16 + cb;
        bv[nf] = benc[col]; gv[nf] = gma[col]; btv[nf] = bta[col];
    }
    float h[2][4][4];
    #pragma unroll
    for (int mi = 0; mi < 2; ++mi)
        #pragma unroll
        for (int r = 0; r < 4; ++r) {
            float s = 0.f;
            #pragma unroll
            for (int nf = 0; nf < 4; ++nf) {
                h[mi][r][nf] = acc[mi][nf][r] + bv[nf];
                s += h[mi][r][nf];
            }
            s += __shfl_xor(s, 1); s += __shfl_xor(s, 2);
            s += __shfl_xor(s, 4); s += __shfl_xor(s, 8);
            if (cb == 0) red[0][wr * 32 + mi * 16 + rg * 4 + r][wc] = s;
        }
    __syncthreads();
    #pragma unroll
    for (int mi = 0; mi < 2; ++mi)
        #pragma unroll
        for (int r = 0; r < 4; ++r) {
            const int rl = wr * 32 + mi * 16 + rg * 4 + r;
            const float mu = (red[0][rl][0] + red[0][rl][1]) * (1.f / 128.f);
            float s2 = 0.f;
            #pragma unroll
            for (int nf = 0; nf < 4; ++nf) {
                h[mi][r][nf] -= mu;
                s2 += h[mi][r][nf] * h[mi][r][nf];
            }
            s2 += __shfl_xor(s2, 1); s2 += __shfl_xor(s2, 2);
            s2 += __shfl_xor(s2, 4); s2 += __shfl_xor(s2, 8);
            if (cb == 0) red[1][rl][wc] = s2;
        }
    __syncthreads();
    #pragma unroll
    for (int mi = 0; mi < 2; ++mi)
        #pragma unroll
        for (int r = 0; r < 4; ++r) {
            const int rl = wr * 32 + mi * 16 + rg * 4 + r;
            const int t = t0 + rl;
            const float var = (red[1][rl][0] + red[1][rl][1]) * (1.f / 128.f);
            const float rstd = 1.f / sqrtf(var + kEps);
            if (t < kNwin) {
                unsigned* dst = encp + ((size_t)(b * kS + t)) * kH;
                #pragma unroll
                for (int nf = 0; nf < 4; ++nf) {
                    float v = gelu_exact(h[mi][r][nf] * rstd * gv[nf] + btv[nf]);
                    unsigned short hi, lo;
                    split2(v, hi, lo);
                    dst[wc * 64 + nf * 16 + cb] = (unsigned)hi | ((unsigned)lo << 16);
                }
            }
        }
}

// ================= comparator (512 thr): L1 16r x 64c, L2 16r x 32c, frag-major W =================
// pool (ush): phase1: esh@0 (64*72=4608) | esl@4608 | wt1h@9216 (8192) | wt1l@17408 -> 25600
//             phase2: z1h@0 (64*136) | z1l@8704 | w2h@17408 (4096) | w2l@21504 -> 25600
//             phase3: z2f f32 @0
constexpr int EPP = 72;

__global__ __launch_bounds__(512, 4)
void cmp_kernel(const unsigned* __restrict__ encp,
                const unsigned short* __restrict__ W1Fh, const unsigned short* __restrict__ W1Fl,
                const float* __restrict__ b1,
                const unsigned short* __restrict__ W2Fh, const unsigned short* __restrict__ W2Fl,
                const float* __restrict__ b2, const float* __restrict__ W3,
                const float* __restrict__ b3, float* __restrict__ out,
                int* __restrict__ fcnt, unsigned* __restrict__ flist)
{
    __shared__ __align__(16) unsigned short pool[25600];   // 51.2 KB
    __shared__ float prm[192];

    unsigned short* esh  = pool;
    unsigned short* esl  = pool + 4608;
    unsigned short* wt1h = pool + 9216;
    unsigned short* wt1l = pool + 17408;

    const int tid = threadIdx.x, b = blockIdx.y, t0 = blockIdx.x * 64;
    const int l = tid & 63, w = tid >> 6;
    const int wr = w >> 1, wc = w & 1;
    const int cb = l & 15, rg = l >> 4;

    if (tid < 128) prm[tid] = b1[tid];
    else if (tid < 192) prm[tid] = b2[tid - 128];

    // ---- layer 1: A[t][k] = enc[t + (k<128?0:20)][k&127], K=256 in 4 chunks of 64
    f32x4 acc1[4];
    #pragma unroll
    for (int nf = 0; nf < 4; ++nf) acc1[nf] = f32x4{0.f, 0.f, 0.f, 0.f};

    for (int kc = 0; kc < 4; ++kc) {
        const int ro = (kc < 2) ? 0 : kW, co = (kc & 1) * 64;
        __syncthreads();
        // W1 chunk: 8192 ush per buffer = 2 DMA rounds of 8 waves
        GLD16(W1Fh + (size_t)kc * 8192 + w * 512 + l * 8, &wt1h[w * 512]);
        GLD16(W1Fh + (size_t)kc * 8192 + 4096 + w * 512 + l * 8, &wt1h[4096 + w * 512]);
        GLD16(W1Fl + (size_t)kc * 8192 + w * 512 + l * 8, &wt1l[w * 512]);
        GLD16(W1Fl + (size_t)kc * 8192 + 4096 + w * 512 + l * 8, &wt1l[4096 + w * 512]);
        {   // stage enc slice: 64 rows x 64 packed u32 -> hi/lo (8 thr/row, 8 u32 each)
            const int r = tid >> 3, qq = tid & 7;
            int gr = t0 + ro + r; if (gr > kNwin - 1) gr = kNwin - 1;
            const unsigned* src = encp + ((size_t)(b * kS + gr)) * kH + co + qq * 8;
            const uint4 v0 = *reinterpret_cast<const uint4*>(src);
            const uint4 v1 = *reinterpret_cast<const uint4*>(src + 4);
            *reinterpret_cast<uint2*>(&esh[r * EPP + qq * 8]) =
                make_uint2((v0.x & 0xFFFFu) | ((v0.y & 0xFFFFu) << 16),
                           (v0.z & 0xFFFFu) | ((v0.w & 0xFFFFu) << 16));
            *reinterpret_cast<uint2*>(&esh[r * EPP + qq * 8 + 4]) =
                make_uint2((v1.x & 0xFFFFu) | ((v1.y & 0xFFFFu) << 16),
                           (v1.z & 0xFFFFu) | ((v1.w & 0xFFFFu) << 16));
            *reinterpret_cast<uint2*>(&esl[r * EPP + qq * 8]) =
                make_uint2((v0.x >> 16) | (v0.y & 0xFFFF0000u),
                           (v0.z >> 16) | (v0.w & 0xFFFF0000u));
            *reinterpret_cast<uint2*>(&esl[r * EPP + qq * 8 + 4]) =
                make_uint2((v1.x >> 16) | (v1.y & 0xFFFF0000u),
                           (v1.z >> 16) | (v1.w & 0xFFFF0000u));
        }
        __syncthreads();
        #pragma unroll
        for (int ks = 0; ks < 2; ++ks) {
            const int ao = (wr * 16 + cb) * EPP + ks * 32 + rg * 8;
            short8 ah = *reinterpret_cast<const short8*>(&esh[ao]);
            short8 al = *reinterpret_cast<const short8*>(&esl[ao]);
            #pragma unroll
            for (int nf = 0; nf < 4; ++nf) {
                const int bo = (ks * 4 + rg) * 1024 + (wc * 64 + nf * 16 + cb) * 8;
                short8 bh = *reinterpret_cast<const short8*>(&wt1h[bo]);
                short8 bl = *reinterpret_cast<const short8*>(&wt1l[bo]);
                acc1[nf] = __builtin_amdgcn_mfma_f32_16x16x32_bf16(ah, bh, acc1[nf], 0, 0, 0);
                acc1[nf] = __builtin_amdgcn_mfma_f32_16x16x32_bf16(al, bh, acc1[nf], 0, 0, 0);
                acc1[nf] = __builtin_amdgcn_mfma_f32_16x16x32_bf16(ah, bl, acc1[nf], 0, 0, 0);
            }
        }
    }
    __syncthreads();     // all es/wt1 reads done; z1 overlays
    unsigned short* z1h = pool;
    unsigned short* z1l = pool + 8704;
    unsigned short* w2h = pool + 17408;
    unsigned short* w2l = pool + 21504;
    #pragma unroll
    for (int r = 0; r < 4; ++r) {
        const int row = wr * 16 + rg * 4 + r;
        #pragma unroll
        for (int nf = 0; nf < 4; ++nf) {
            const int col = wc * 64 + nf * 16 + cb;
            float v = gelu_exact(acc1[nf][r] + prm[col]);
            unsigned short hi, lo;
            split2(v, hi, lo);
            z1h[row * 136 + col] = hi;
            z1l[row * 136 + col] = lo;
        }
    }

    // ---- layer 2: K=128 in 2 chunks of 64, N=64; wave tile 16r x 32c
    f32x4 acc2[2];
    #pragma unroll
    for (int nf = 0; nf < 2; ++nf) acc2[nf] = f32x4{0.f, 0.f, 0.f, 0.f};

    for (int kc2 = 0; kc2 < 2; ++kc2) {
        __syncthreads();
        GLD16(W2Fh + (size_t)kc2 * 4096 + w * 512 + l * 8, &w2h[w * 512]);
        GLD16(W2Fl + (size_t)kc2 * 4096 + w * 512 + l * 8, &w2l[w * 512]);
        __syncthreads();
        #pragma unroll
        for (int ks = 0; ks < 2; ++ks) {
            const int ao = (wr * 16 + cb) * 136 + kc2 * 64 + ks * 32 + rg * 8;
            short8 ah = *reinterpret_cast<const short8*>(&z1h[ao]);
            short8 al = *reinterpret_cast<const short8*>(&z1l[ao]);
            #pragma unroll
            for (int nf = 0; nf < 2; ++nf) {
                const int bo = (ks * 4 + rg) * 512 + (wc * 32 + nf * 16 + cb) * 8;
                short8 bh = *reinterpret_cast<const short8*>(&w2h[bo]);
                short8 bl = *reinterpret_cast<const short8*>(&w2l[bo]);
                acc2[nf] = __builtin_amdgcn_mfma_f32_16x16x32_bf16(ah, bh, acc2[nf], 0, 0, 0);
                acc2[nf] = __builtin_amdgcn_mfma_f32_16x16x32_bf16(al, bh, acc2[nf], 0, 0, 0);
                acc2[nf] = __builtin_amdgcn_mfma_f32_16x16x32_bf16(ah, bl, acc2[nf], 0, 0, 0);
            }
        }
    }
    __syncthreads();     // z1/w2 reads done; z2f overlays
    float* z2f = reinterpret_cast<float*>(pool);   // 64 x 68 f32
    #pragma unroll
    for (int r = 0; r < 4; ++r) {
        const int row = wr * 16 + rg * 4 + r;
        #pragma unroll
        for (int nf = 0; nf < 2; ++nf) {
            const int col = wc * 32 + nf * 16 + cb;
            z2f[row * 68 + col] = gelu_exact(acc2[nf][r] + prm[128 + col]);
        }
    }
    __syncthreads();

    // ---- layer 3: dot + sigmoid; flag borderline
    if (tid < 64) {
        const int t = t0 + tid;
        if (t < kT) {
            float s = 0.f;
            #pragma unroll 8
            for (int k = 0; k < 64; ++k) s = fmaf(z2f[tid * 68 + k], W3[k], s);
            const float p = 1.f / (1.f + expf(-(s + b3[0])));
            out[(size_t)b * kS + t + kW] = p;
            out[(size_t)kB * kS + (size_t)b * kS + t + kW] = (p > 0.5f) ? 1.f : 0.f;
            if (fabsf(p - 0.5f) < kMargin) {
                int idx = atomicAdd(fcnt, 1);
                if (idx < FCAP) flist[idx] = ((unsigned)b << 16) | (unsigned)t;
            }
        }
    }
}

// ================= fix2: full fp32 recompute per flagged position =================
__global__ __launch_bounds__(256, 4)
void fix2_kernel(const float* __restrict__ x, const float* __restrict__ Wenc,
                 const float* __restrict__ benc, const float* __restrict__ gma,
                 const float* __restrict__ bta, const float* __restrict__ W1,
                 const float* __restrict__ b1, const float* __restrict__ W2,
                 const float* __restrict__ b2, const float* __restrict__ W3,
                 const float* __restrict__ b3, const int* __restrict__ fcnt,
                 const unsigned* __restrict__ flist, float* __restrict__ out)
{
    __shared__ float xw[1280];
    __shared__ float es[256];
    __shared__ float z1s[128];
    __shared__ float z2s[64];
    __shared__ float wred[4];

    const int tid = threadIdx.x;
    int n = *fcnt; if (n > FCAP) n = FCAP;

    for (int i = blockIdx.x; i < n; i += gridDim.x) {
        const unsigned e = flist[i];
        const int b = (int)(e >> 16), t = (int)(e & 0xFFFF);
        __syncthreads();
        for (int j = tid; j < 320; j += 256) {
            int r = (j >= 160) ? 1 : 0, u = j - r * 160;
            const float4 v = *reinterpret_cast<const float4*>(
                x + ((size_t)b * kS + t + r * kW) * kI + u * 4);
            *reinterpret_cast<float4*>(&xw[r * 640 + u * 4]) = v;
        }
        __syncthreads();
        const int r = tid >> 7, c = tid & 127;
        float h = 0.f;
        const float* xr = &xw[r * 640];
        #pragma unroll 16
        for (int k = 0; k < 640; ++k) h = fmaf(xr[k], Wenc[(size_t)k * kH + c], h);
        h += benc[c];
        float s = h;
        #pragma unroll
        for (int m = 1; m < 64; m <<= 1) s += __shfl_xor(s, m, 64);
        if ((tid & 63) == 0) wred[tid >> 6] = s;
        __syncthreads();
        const float mu = (wred[r * 2] + wred[r * 2 + 1]) * (1.f / 128.f);
        const float d = h - mu;
        float s2 = d * d;
        #pragma unroll
        for (int m = 1; m < 64; m <<= 1) s2 += __shfl_xor(s2, m, 64);
        __syncthreads();
        if ((tid & 63) == 0) wred[tid >> 6] = s2;
        __syncthreads();
        const float var = (wred[r * 2] + wred[r * 2 + 1]) * (1.f / 128.f);
        es[tid] = gelu_exact(d * (1.f / sqrtf(var + kEps)) * gma[c] + bta[c]);
        __syncthreads();
        if (tid < kH) {
            float z = 0.f;
            #pragma unroll 16
            for (int k = 0; k < 256; ++k) z = fmaf(es[k], W1[(size_t)k * kH + tid], z);
            z1s[tid] = gelu_exact(z + b1[tid]);
        }
        __syncthreads();
        if (tid < 64) {
            float z = 0.f;
            #pragma unroll 16
            for (int k = 0; k < kH; ++k) z = fmaf(z1s[k], W2[(size_t)k * 64 + tid], z);
            z2s[tid] = gelu_exact(z + b2[tid]);
        }
        __syncthreads();
        if (tid < 64) {
            float s3 = z2s[tid] * W3[tid];
            #pragma unroll
            for (int m = 1; m < 64; m <<= 1) s3 += __shfl_xor(s3, m, 64);
            if (tid == 0) {
                const float p = 1.f / (1.f + expf(-(s3 + b3[0])));
                out[(size_t)b * kS + t + kW] = p;
                out[(size_t)kB * kS + (size_t)b * kS + t + kW] = (p > 0.5f) ? 1.f : 0.f;
            }
        }
        __syncthreads();
    }
}

}  // namespace

extern "C" void kernel_launch(void* const* d_in, const int* in_sizes, int n_in,
                              void* d_out, int out_size, void* d_ws, size_t ws_size,
                              hipStream_t stream)
{
    const float* x    = (const float*)d_in[0];
    const float* Wenc = (const float*)d_in[1];
    const float* benc = (const float*)d_in[2];
    const float* gma  = (const float*)d_in[3];
    const float* bta  = (const float*)d_in[4];
    const float* W1   = (const float*)d_in[5];
    const float* b1   = (const float*)d_in[6];
    const float* W2   = (const float*)d_in[7];
    const float* b2   = (const float*)d_in[8];
    const float* W3   = (const float*)d_in[9];
    const float* b3   = (const float*)d_in[10];
    float* out = (float*)d_out;

    char* ws = (char*)d_ws;
    unsigned* encp        = (unsigned*)(ws + ENCP_OFF);
    unsigned short* WeFh  = (unsigned short*)(ws + WETH_OFF);
    unsigned short* WeFl  = (unsigned short*)(ws + WETL_OFF);
    unsigned short* W1Fh  = (unsigned short*)(ws + W1TH_OFF);
    unsigned short* W1Fl  = (unsigned short*)(ws + W1TL_OFF);
    unsigned short* W2Fh  = (unsigned short*)(ws + W2TH_OFF);
    unsigned short* W2Fl  = (unsigned short*)(ws + W2TL_OFF);
    int* fcnt             = (int*)(ws + FC_OFF);
    unsigned* flist       = (unsigned*)(ws + FL_OFF);

    hipMemsetAsync(d_out, 0, (size_t)out_size * sizeof(float), stream);
    hipMemsetAsync(fcnt, 0, 64, stream);

    prep_kernel<<<256, 256, 0, stream>>>(Wenc, W1, W2, WeFh, WeFl, W1Fh, W1Fl, W2Fh, W2Fl);
    enc_kernel<<<dim3(16, kB), 512, 0, stream>>>(x, WeFh, WeFl, benc, gma, bta, encp);
    cmp_kernel<<<dim3(32, kB), 512, 0, stream>>>(encp, W1Fh, W1Fl, b1, W2Fh, W2Fl, b2,
                                                 W3, b3, out, fcnt, flist);
    fix2_kernel<<<4096, 256, 0, stream>>>(x, Wenc, benc, gma, bta, W1, b1, W2, b2, W3, b3,
                                          fcnt, flist, out);
}